// Round 1
// baseline (58.910 us; speedup 1.0000x reference)
//
#include <hip/hip_runtime.h>
#include <hip/hip_bf16.h>

#define IMG_H 512
#define IMG_W 512
#define N_PLANES 48                      // 16 batch * 3 channels
#define TOTAL_ELEMS (48LL * 512 * 512)   // 12582912

// Load 6 consecutive floats of one row (cols x0-1 .. x0+4) with zero padding.
// Center 4 floats are a 16B-aligned float4 (x0 is a multiple of 4).
__device__ __forceinline__ void load_row6(const float* __restrict__ p, int y, int x0,
                                          float r[6]) {
    if ((unsigned)y < (unsigned)IMG_H) {
        const float* row = p + (size_t)y * IMG_W;
        const float4 v = *reinterpret_cast<const float4*>(row + x0);
        r[0] = (x0 > 0) ? row[x0 - 1] : 0.0f;
        r[1] = v.x; r[2] = v.y; r[3] = v.z; r[4] = v.w;
        r[5] = (x0 + 4 < IMG_W) ? row[x0 + 4] : 0.0f;
    } else {
        r[0] = r[1] = r[2] = r[3] = r[4] = r[5] = 0.0f;
    }
}

__device__ __forceinline__ float sobel_mag(const float t[6], const float m[6],
                                           const float b[6], int j) {
    // kx = [[-1,0,1],[-2,0,2],[-1,0,1]], ky = [[-1,-2,-1],[0,0,0],[1,2,1]]
    float ex = (t[j + 2] - t[j]) + 2.0f * (m[j + 2] - m[j]) + (b[j + 2] - b[j]);
    float ey = (b[j] + 2.0f * b[j + 1] + b[j + 2]) - (t[j] + 2.0f * t[j + 1] + t[j + 2]);
    return sqrtf(ex * ex + ey * ey + 1e-6f);
}

// Block: 256 threads = 128 x-threads (4 px wide each) x 2 y-threads (4 rows each).
// Block tile: 512 wide x 8 tall.  Grid: (512/8 = 64 row-blocks, 48 planes).
__global__ __launch_bounds__(256) void edge_loss_kernel(const float* __restrict__ img1,
                                                        const float* __restrict__ img2,
                                                        float* __restrict__ acc) {
    const int t  = threadIdx.x;
    const int tx = t & 127;        // 0..127
    const int ty = t >> 7;         // 0..1
    const int x0 = tx << 2;        // 0..508, multiple of 4
    const int y0 = blockIdx.x * 8 + ty * 4;
    const size_t base = (size_t)blockIdx.y * (IMG_H * IMG_W);
    const float* p1 = img1 + base;
    const float* p2 = img2 + base;

    float a[6][6], b[6][6];
#pragma unroll
    for (int r = 0; r < 6; ++r) {
        load_row6(p1, y0 - 1 + r, x0, a[r]);
        load_row6(p2, y0 - 1 + r, x0, b[r]);
    }

    float sum = 0.0f;
#pragma unroll
    for (int r = 0; r < 4; ++r) {
#pragma unroll
        for (int j = 0; j < 4; ++j) {
            float m1 = sobel_mag(a[r], a[r + 1], a[r + 2], j);
            float m2 = sobel_mag(b[r], b[r + 1], b[r + 2], j);
            sum += fabsf(m1 - m2);
        }
    }

    // wave (64-lane) butterfly reduce
#pragma unroll
    for (int off = 32; off > 0; off >>= 1) sum += __shfl_down(sum, off);

    __shared__ float wave_sums[4];
    const int wave = t >> 6;
    if ((t & 63) == 0) wave_sums[wave] = sum;
    __syncthreads();
    if (t == 0) {
        float s = (wave_sums[0] + wave_sums[1]) + (wave_sums[2] + wave_sums[3]);
        atomicAdd(acc, s);   // device-scope by default on CDNA
    }
}

__global__ void finalize_kernel(const float* __restrict__ acc, float* __restrict__ out) {
    out[0] = acc[0] * (1.0f / (float)TOTAL_ELEMS);
}

extern "C" void kernel_launch(void* const* d_in, const int* in_sizes, int n_in,
                              void* d_out, int out_size, void* d_ws, size_t ws_size,
                              hipStream_t stream) {
    const float* img1 = (const float*)d_in[0];
    const float* img2 = (const float*)d_in[1];
    float* out = (float*)d_out;
    float* acc = (float*)d_ws;

    hipMemsetAsync(acc, 0, sizeof(float), stream);   // capture-safe (memset node)
    edge_loss_kernel<<<dim3(64, 48), 256, 0, stream>>>(img1, img2, acc);
    finalize_kernel<<<1, 1, 0, stream>>>(acc, out);
}

// Round 2
// 43.351 us; speedup vs baseline: 1.3589x; 1.3589x over previous
//
#include <hip/hip_runtime.h>
#include <hip/hip_bf16.h>

#define IMG_H 512
#define IMG_W 512
#define TOTAL_ELEMS (48LL * 512 * 512)   // 16*3*512*512

struct Row { float v[8]; float eL, eR; };

// One wave (64 lanes x 8 cols) covers a full 512-wide row. Coalesced float4
// pairs; column halo via 2 wave shuffles (no scalar edge loads).
__device__ __forceinline__ void load_row(const float* __restrict__ plane, int y, int x0,
                                         int lane, Row& r) {
    if ((unsigned)y < (unsigned)IMG_H) {   // wave-uniform branch
        const float* row = plane + (size_t)y * IMG_W + x0;
        const float4 a = *reinterpret_cast<const float4*>(row);
        const float4 b = *reinterpret_cast<const float4*>(row + 4);
        r.v[0] = a.x; r.v[1] = a.y; r.v[2] = a.z; r.v[3] = a.w;
        r.v[4] = b.x; r.v[5] = b.y; r.v[6] = b.z; r.v[7] = b.w;
    } else {
#pragma unroll
        for (int i = 0; i < 8; ++i) r.v[i] = 0.0f;
    }
    const float up = __shfl_up(r.v[7], 1);    // lane l-1's col x0-1
    const float dn = __shfl_down(r.v[0], 1);  // lane l+1's col x0+8
    r.eL = (lane == 0) ? 0.0f : up;           // zero padding at col -1
    r.eR = (lane == 63) ? 0.0f : dn;          // zero padding at col 512
}

// Separable Sobel for one output row (8 px/lane) from rows t(y-1), m(y), b(y+1).
__device__ __forceinline__ void sobel_row(const Row& t, const Row& m, const Row& b,
                                          float mag[8]) {
    float cs[10], rd[10];                      // static-indexed after unroll
    cs[0] = t.eL + 2.0f * m.eL + b.eL;
    rd[0] = b.eL - t.eL;
#pragma unroll
    for (int j = 0; j < 8; ++j) {
        cs[j + 1] = t.v[j] + 2.0f * m.v[j] + b.v[j];   // vertical [1,2,1]
        rd[j + 1] = b.v[j] - t.v[j];                   // vertical [-1,0,1]
    }
    cs[9] = t.eR + 2.0f * m.eR + b.eR;
    rd[9] = b.eR - t.eR;
#pragma unroll
    for (int j = 0; j < 8; ++j) {
        const float ex = cs[j + 2] - cs[j];                          // horiz [-1,0,1]
        const float ey = rd[j] + 2.0f * rd[j + 1] + rd[j + 2];       // horiz [1,2,1]
        mag[j] = sqrtf(ex * ex + ey * ey + 1e-6f);
    }
}

// Block = 4 waves; each wave = one 8-row x 512-col strip of one plane.
// Grid: 48 planes * 64 strips / 4 = 768 blocks.
__global__ __launch_bounds__(256) void edge_loss_kernel(const float* __restrict__ img1,
                                                        const float* __restrict__ img2,
                                                        float* __restrict__ acc) {
    const int t = threadIdx.x;
    const int lane = t & 63;
    const int wave = t >> 6;
    const int wid = blockIdx.x * 4 + wave;
    const int plane = wid >> 6;          // 64 strips per plane
    const int strip = wid & 63;
    const int x0 = lane << 3;
    const int y0 = strip << 3;
    const size_t base = (size_t)plane * (IMG_H * IMG_W);
    const float* p1 = img1 + base;
    const float* p2 = img2 + base;

    Row a[4], b[4];                      // 4-slot ring, static indices via unroll
    load_row(p1, y0 - 1, x0, lane, a[0]); load_row(p2, y0 - 1, x0, lane, b[0]);
    load_row(p1, y0,     x0, lane, a[1]); load_row(p2, y0,     x0, lane, b[1]);
    load_row(p1, y0 + 1, x0, lane, a[2]); load_row(p2, y0 + 1, x0, lane, b[2]);

    float sum = 0.0f;
#pragma unroll
    for (int r = 0; r < 8; ++r) {
        if (r < 7) {                     // depth-1 prefetch of next bottom row
            load_row(p1, y0 + 2 + r, x0, lane, a[(r + 3) & 3]);
            load_row(p2, y0 + 2 + r, x0, lane, b[(r + 3) & 3]);
        }
        float m1[8], m2[8];
        sobel_row(a[r & 3], a[(r + 1) & 3], a[(r + 2) & 3], m1);
        sobel_row(b[r & 3], b[(r + 1) & 3], b[(r + 2) & 3], m2);
#pragma unroll
        for (int j = 0; j < 8; ++j) sum += fabsf(m1[j] - m2[j]);
    }

#pragma unroll
    for (int off = 32; off > 0; off >>= 1) sum += __shfl_down(sum, off);

    __shared__ float wave_sums[4];
    if (lane == 0) wave_sums[wave] = sum;
    __syncthreads();
    if (t == 0) {
        atomicAdd(acc, (wave_sums[0] + wave_sums[1]) + (wave_sums[2] + wave_sums[3]));
    }
}

__global__ void finalize_kernel(const float* __restrict__ acc, float* __restrict__ out) {
    out[0] = acc[0] * (1.0f / (float)TOTAL_ELEMS);
}

extern "C" void kernel_launch(void* const* d_in, const int* in_sizes, int n_in,
                              void* d_out, int out_size, void* d_ws, size_t ws_size,
                              hipStream_t stream) {
    const float* img1 = (const float*)d_in[0];
    const float* img2 = (const float*)d_in[1];
    float* out = (float*)d_out;
    float* acc = (float*)d_ws;

    hipMemsetAsync(acc, 0, sizeof(float), stream);
    edge_loss_kernel<<<dim3(768), 256, 0, stream>>>(img1, img2, acc);
    finalize_kernel<<<1, 1, 0, stream>>>(acc, out);
}

// Round 3
// 42.984 us; speedup vs baseline: 1.3705x; 1.0085x over previous
//
#include <hip/hip_runtime.h>
#include <hip/hip_bf16.h>

#define IMG_H 512
#define IMG_W 512
#define TOTAL_ELEMS (48LL * 512 * 512)   // 16*3*512*512

// Per output row: vertical pass (column-sum cs, row-diff rd), then horizontal
// pass with column halo pulled from neighbor lanes via shuffles on cs/rd
// (legal because both are linear in the inputs; zero-pad at image edge).
__device__ __forceinline__ float row_absdiff(const float t1[8], const float m1[8], const float b1[8],
                                             const float t2[8], const float m2[8], const float b2[8],
                                             int lane) {
    float cs1[8], rd1[8], cs2[8], rd2[8];
#pragma unroll
    for (int j = 0; j < 8; ++j) {
        cs1[j] = t1[j] + 2.0f * m1[j] + b1[j];
        rd1[j] = b1[j] - t1[j];
        cs2[j] = t2[j] + 2.0f * m2[j] + b2[j];
        rd2[j] = b2[j] - t2[j];
    }
    float cs1L = __shfl_up(cs1[7], 1), cs1R = __shfl_down(cs1[0], 1);
    float rd1L = __shfl_up(rd1[7], 1), rd1R = __shfl_down(rd1[0], 1);
    float cs2L = __shfl_up(cs2[7], 1), cs2R = __shfl_down(cs2[0], 1);
    float rd2L = __shfl_up(rd2[7], 1), rd2R = __shfl_down(rd2[0], 1);
    if (lane == 0)  { cs1L = rd1L = cs2L = rd2L = 0.0f; }   // col -1 zero pad
    if (lane == 63) { cs1R = rd1R = cs2R = rd2R = 0.0f; }   // col 512 zero pad
    float s = 0.0f;
#pragma unroll
    for (int j = 0; j < 8; ++j) {
        const float csm1 = (j == 0) ? cs1L : cs1[j - 1], csp1 = (j == 7) ? cs1R : cs1[j + 1];
        const float rdm1 = (j == 0) ? rd1L : rd1[j - 1], rdp1 = (j == 7) ? rd1R : rd1[j + 1];
        const float csm2 = (j == 0) ? cs2L : cs2[j - 1], csp2 = (j == 7) ? cs2R : cs2[j + 1];
        const float rdm2 = (j == 0) ? rd2L : rd2[j - 1], rdp2 = (j == 7) ? rd2R : rd2[j + 1];
        const float ex1 = csp1 - csm1;
        const float ey1 = rdm1 + 2.0f * rd1[j] + rdp1;
        const float mg1 = sqrtf(ex1 * ex1 + ey1 * ey1 + 1e-6f);
        const float ex2 = csp2 - csm2;
        const float ey2 = rdm2 + 2.0f * rd2[j] + rdp2;
        const float mg2 = sqrtf(ex2 * ex2 + ey2 * ey2 + 1e-6f);
        s += fabsf(mg1 - mg2);
    }
    return s;
}

// One wave = one 4-row x 512-col strip (8 cols/lane). All 24 float4 loads for
// the 6-row x 2-image window issue back-to-back (clamped y, no branches) for
// maximum memory-level parallelism; OOB rows zeroed after (wave-uniform).
// Grid: 48 planes * 128 strips / 4 waves per block = 1536 blocks.
__global__ __launch_bounds__(256) void edge_loss_kernel(const float* __restrict__ img1,
                                                        const float* __restrict__ img2,
                                                        float* __restrict__ acc) {
    const int t = threadIdx.x;
    const int lane = t & 63;
    const int wave = t >> 6;
    const int wid = blockIdx.x * 4 + wave;
    const int plane = wid >> 7;          // 128 strips per plane
    const int strip = wid & 127;
    const int x0 = lane << 3;
    const int y0 = strip << 2;
    const size_t base = (size_t)plane * (IMG_H * IMG_W);
    const float* p1 = img1 + base;
    const float* p2 = img2 + base;

    float a[6][8], b[6][8];
#pragma unroll
    for (int r = 0; r < 6; ++r) {
        const int y = y0 - 1 + r;
        const int yc = y < 0 ? 0 : (y > IMG_H - 1 ? IMG_H - 1 : y);
        const float* r1 = p1 + (size_t)yc * IMG_W + x0;
        const float* r2 = p2 + (size_t)yc * IMG_W + x0;
        const float4 a0 = *reinterpret_cast<const float4*>(r1);
        const float4 a1 = *reinterpret_cast<const float4*>(r1 + 4);
        const float4 b0 = *reinterpret_cast<const float4*>(r2);
        const float4 b1 = *reinterpret_cast<const float4*>(r2 + 4);
        a[r][0] = a0.x; a[r][1] = a0.y; a[r][2] = a0.z; a[r][3] = a0.w;
        a[r][4] = a1.x; a[r][5] = a1.y; a[r][6] = a1.z; a[r][7] = a1.w;
        b[r][0] = b0.x; b[r][1] = b0.y; b[r][2] = b0.z; b[r][3] = b0.w;
        b[r][4] = b1.x; b[r][5] = b1.y; b[r][6] = b1.z; b[r][7] = b1.w;
    }
    if (y0 == 0) {                       // top image border: row -1 is zero pad
#pragma unroll
        for (int j = 0; j < 8; ++j) a[0][j] = b[0][j] = 0.0f;
    }
    if (y0 + 4 == IMG_H) {               // bottom image border: row 512 is zero pad
#pragma unroll
        for (int j = 0; j < 8; ++j) a[5][j] = b[5][j] = 0.0f;
    }

    float sum = 0.0f;
#pragma unroll
    for (int o = 0; o < 4; ++o)
        sum += row_absdiff(a[o], a[o + 1], a[o + 2], b[o], b[o + 1], b[o + 2], lane);

#pragma unroll
    for (int off = 32; off > 0; off >>= 1) sum += __shfl_down(sum, off);

    __shared__ float wave_sums[4];
    if (lane == 0) wave_sums[wave] = sum;
    __syncthreads();
    if (t == 0) {
        atomicAdd(acc, (wave_sums[0] + wave_sums[1]) + (wave_sums[2] + wave_sums[3]));
    }
}

__global__ void finalize_kernel(const float* __restrict__ acc, float* __restrict__ out) {
    out[0] = acc[0] * (1.0f / (float)TOTAL_ELEMS);
}

extern "C" void kernel_launch(void* const* d_in, const int* in_sizes, int n_in,
                              void* d_out, int out_size, void* d_ws, size_t ws_size,
                              hipStream_t stream) {
    const float* img1 = (const float*)d_in[0];
    const float* img2 = (const float*)d_in[1];
    float* out = (float*)d_out;
    float* acc = (float*)d_ws;

    hipMemsetAsync(acc, 0, sizeof(float), stream);
    edge_loss_kernel<<<dim3(1536), 256, 0, stream>>>(img1, img2, acc);
    finalize_kernel<<<1, 1, 0, stream>>>(acc, out);
}

// Round 4
// 32.023 us; speedup vs baseline: 1.8396x; 1.3423x over previous
//
#include <hip/hip_runtime.h>
#include <hip/hip_bf16.h>

#define IMG_H 512
#define IMG_W 512
#define TOTAL_ELEMS (48LL * 512 * 512)   // 16*3*512*512

__device__ __forceinline__ float fast_sqrtf(float x) {
    float r; asm("v_sqrt_f32 %0, %1" : "=v"(r) : "v"(x)); return r;   // ~1 ulp, plenty for 1.4e-2 threshold
}

__device__ __forceinline__ void load8(const float* __restrict__ p, float v[8]) {
    const float4 x = *reinterpret_cast<const float4*>(p);
    const float4 y = *reinterpret_cast<const float4*>(p + 4);
    v[0] = x.x; v[1] = x.y; v[2] = x.z; v[3] = x.w;
    v[4] = y.x; v[5] = y.y; v[6] = y.z; v[7] = y.w;
}

__device__ __forceinline__ void lds_read8(const float* __restrict__ s, float v[8]) {
    const float4 x = *reinterpret_cast<const float4*>(s);
    const float4 y = *reinterpret_cast<const float4*>(s + 4);
    v[0] = x.x; v[1] = x.y; v[2] = x.z; v[3] = x.w;
    v[4] = y.x; v[5] = y.y; v[6] = y.z; v[7] = y.w;
}

// Separable Sobel magnitude for one output row (8 px/lane); column halo via
// 2 shuffles on the linear vertical-pass terms (zero pad at image edges).
__device__ __forceinline__ void sobel_mag_row(const float t[8], const float m[8], const float b[8],
                                              int lane, float mag[8]) {
    float cs[8], rd[8];
#pragma unroll
    for (int j = 0; j < 8; ++j) {
        cs[j] = (t[j] + b[j]) + 2.0f * m[j];   // vertical [1,2,1]
        rd[j] = b[j] - t[j];                   // vertical [-1,0,1]
    }
    float csL = __shfl_up(cs[7], 1), csR = __shfl_down(cs[0], 1);
    float rdL = __shfl_up(rd[7], 1), rdR = __shfl_down(rd[0], 1);
    if (lane == 0)  { csL = 0.0f; rdL = 0.0f; }
    if (lane == 63) { csR = 0.0f; rdR = 0.0f; }
#pragma unroll
    for (int j = 0; j < 8; ++j) {
        const float ex = ((j == 7) ? csR : cs[j + 1]) - ((j == 0) ? csL : cs[j - 1]);
        const float ey = ((j == 0) ? rdL : rd[j - 1]) + 2.0f * rd[j] + ((j == 7) ? rdR : rd[j + 1]);
        mag[j] = fast_sqrtf(fmaf(ex, ex, fmaf(ey, ey, 1e-6f)));
    }
}

// Block = 4 waves = one 16-row x 512-col tile of one plane. Each wave loads
// ONLY its 4 rows (+2 global halo rows per block); wave-boundary rows are
// exchanged via LDS -> read amplification 1.125x (was 1.5x).
// Grid: 48 planes * 32 blocks/plane = 1536 blocks, XCD-swizzled (1536 = 8*192).
__global__ __launch_bounds__(256) void edge_loss_kernel(const float* __restrict__ img1,
                                                        const float* __restrict__ img2,
                                                        float* __restrict__ acc) {
    const int t = threadIdx.x;
    const int lane = t & 63;
    const int w = t >> 6;
    const int bid = blockIdx.x;
    const int swz = (bid & 7) * 192 + (bid >> 3);   // XCD k -> contiguous 6 plane-pairs
    const int plane = swz >> 5;                     // 32 blocks per plane
    const int blk = swz & 31;
    const int yb = blk << 4;                        // tile top row
    const int y0 = yb + (w << 2);                   // this wave's first row
    const int x0 = lane << 3;
    const size_t base = (size_t)plane * (IMG_H * IMG_W);
    const float* p1 = img1 + base + x0;
    const float* p2 = img2 + base + x0;

    __shared__ float sh[2][4][2][IMG_W];            // [img][wave][first/last row][col] = 32 KB

    // own rows (8 coalesced float4-pair loads, all independent)
    float a[4][8], b[4][8];
#pragma unroll
    for (int r = 0; r < 4; ++r) {
        load8(p1 + (size_t)(y0 + r) * IMG_W, a[r]);
        load8(p2 + (size_t)(y0 + r) * IMG_W, b[r]);
    }

    // block-edge halo rows from global (waves 0 and 3 only; wave-uniform branch)
    float ha[8], hb[8];
    bool hzero = false;
    if (w == 0) {
        hzero = (yb == 0);
        const int y = hzero ? 0 : yb - 1;
        load8(p1 + (size_t)y * IMG_W, ha);
        load8(p2 + (size_t)y * IMG_W, hb);
    } else if (w == 3) {
        hzero = (yb + 16 == IMG_H);
        const int y = hzero ? IMG_H - 1 : yb + 16;
        load8(p1 + (size_t)y * IMG_W, ha);
        load8(p2 + (size_t)y * IMG_W, hb);
    }
    if ((w == 0 || w == 3) && hzero) {
#pragma unroll
        for (int j = 0; j < 8; ++j) { ha[j] = 0.0f; hb[j] = 0.0f; }
    }

    // publish boundary rows
    *reinterpret_cast<float4*>(&sh[0][w][0][x0])     = make_float4(a[0][0], a[0][1], a[0][2], a[0][3]);
    *reinterpret_cast<float4*>(&sh[0][w][0][x0 + 4]) = make_float4(a[0][4], a[0][5], a[0][6], a[0][7]);
    *reinterpret_cast<float4*>(&sh[0][w][1][x0])     = make_float4(a[3][0], a[3][1], a[3][2], a[3][3]);
    *reinterpret_cast<float4*>(&sh[0][w][1][x0 + 4]) = make_float4(a[3][4], a[3][5], a[3][6], a[3][7]);
    *reinterpret_cast<float4*>(&sh[1][w][0][x0])     = make_float4(b[0][0], b[0][1], b[0][2], b[0][3]);
    *reinterpret_cast<float4*>(&sh[1][w][0][x0 + 4]) = make_float4(b[0][4], b[0][5], b[0][6], b[0][7]);
    *reinterpret_cast<float4*>(&sh[1][w][1][x0])     = make_float4(b[3][0], b[3][1], b[3][2], b[3][3]);
    *reinterpret_cast<float4*>(&sh[1][w][1][x0 + 4]) = make_float4(b[3][4], b[3][5], b[3][6], b[3][7]);
    __syncthreads();

    // assemble halo rows: top = row y0-1, bot = row y0+4 (per image)
    float ta[8], tb[8], ba[8], bb[8];
    if (w == 0) {
#pragma unroll
        for (int j = 0; j < 8; ++j) { ta[j] = ha[j]; tb[j] = hb[j]; }
    } else {
        lds_read8(&sh[0][w - 1][1][x0], ta);
        lds_read8(&sh[1][w - 1][1][x0], tb);
    }
    if (w == 3) {
#pragma unroll
        for (int j = 0; j < 8; ++j) { ba[j] = ha[j]; bb[j] = hb[j]; }
    } else {
        lds_read8(&sh[0][w + 1][0][x0], ba);
        lds_read8(&sh[1][w + 1][0][x0], bb);
    }

    // image 1 magnitudes, then image 2 + abs-diff accumulate
    float m1[4][8];
    sobel_mag_row(ta,   a[0], a[1], lane, m1[0]);
    sobel_mag_row(a[0], a[1], a[2], lane, m1[1]);
    sobel_mag_row(a[1], a[2], a[3], lane, m1[2]);
    sobel_mag_row(a[2], a[3], ba,   lane, m1[3]);

    float sum = 0.0f;
    {
        float m2[8];
        sobel_mag_row(tb,   b[0], b[1], lane, m2);
#pragma unroll
        for (int j = 0; j < 8; ++j) sum += fabsf(m1[0][j] - m2[j]);
        sobel_mag_row(b[0], b[1], b[2], lane, m2);
#pragma unroll
        for (int j = 0; j < 8; ++j) sum += fabsf(m1[1][j] - m2[j]);
        sobel_mag_row(b[1], b[2], b[3], lane, m2);
#pragma unroll
        for (int j = 0; j < 8; ++j) sum += fabsf(m1[2][j] - m2[j]);
        sobel_mag_row(b[2], b[3], bb,   lane, m2);
#pragma unroll
        for (int j = 0; j < 8; ++j) sum += fabsf(m1[3][j] - m2[j]);
    }

#pragma unroll
    for (int off = 32; off > 0; off >>= 1) sum += __shfl_down(sum, off);

    __shared__ float wave_sums[4];
    if (lane == 0) wave_sums[w] = sum;
    __syncthreads();
    if (t == 0) {
        const float s = (wave_sums[0] + wave_sums[1]) + (wave_sums[2] + wave_sums[3]);
        atomicAdd(&acc[(bid & 15) * 16], s);   // 16 slots, 64 B apart: spread contention
    }
}

__global__ void finalize_kernel(const float* __restrict__ acc, float* __restrict__ out) {
    float s = 0.0f;
#pragma unroll
    for (int i = 0; i < 16; ++i) s += acc[i * 16];
    out[0] = s * (1.0f / (float)TOTAL_ELEMS);
}

extern "C" void kernel_launch(void* const* d_in, const int* in_sizes, int n_in,
                              void* d_out, int out_size, void* d_ws, size_t ws_size,
                              hipStream_t stream) {
    const float* img1 = (const float*)d_in[0];
    const float* img2 = (const float*)d_in[1];
    float* out = (float*)d_out;
    float* acc = (float*)d_ws;

    hipMemsetAsync(acc, 0, 16 * 16 * sizeof(float), stream);
    edge_loss_kernel<<<dim3(1536), 256, 0, stream>>>(img1, img2, acc);
    finalize_kernel<<<1, 1, 0, stream>>>(acc, out);
}